// Round 8
// baseline (839.374 us; speedup 1.0000x reference)
//
#include <hip/hip_runtime.h>

// DirectionalFilterBank: 3-level binary tree of (shear ±1 -> depthwise 9x9 conv).
// shear(x,s)[h,w] = 0.5*(x[h,c0]+x[h,c0+1]), c0 = w + s*h + (s>0 ? -128 : 127),
// w in [0,256); conv zero-pads the SHEARED image by 4. Filter rank-2 separable:
// filt_c = -(A (x) A) + (B (x) B) [+ center delta, c==0].
//
// Model R0-R7: no pipe >50% busy (VALU ~7us, LDS ~9us, mem ~10-17us of 35us/conv);
// occupancy-insensitive (R2), traffic-insensitive (R7-corrected: its L2-hit premise
// was false). Diagnosis: PHASE-LOCK -- all resident blocks stage together (VALU
// idle), drain+barrier together, compute together (mem idle); serial launches
// re-lock 14x. THIS ROUND: intra-block 2-tile software pipeline (T14): issue
// tile-1's staging loads into REGISTERS before tile-0's compute -> tile-1 memory
// latency hides under ~2000cy of FMA. Same 41.25KB LDS buffer reused (no double
// buffer): stage0 | issue1 | bar | compute0 | bar | write1 | bar | compute1.
// +50 VGPR across compute0 (~135 tot, __launch_bounds__(256,3) keeps 3 blk/CU).
// Grid 1024/conv (2 tiles per block) -> 1.33 resident-rounds/launch vs 2.67.
// R6's padded intermediates + serial-14 DFS schedule (L3-resident pairs) kept.

#define B_ 4
#define C_ 64
#define H_ 256
#define W_ 256
#define TH 32                 // output rows per tile
#define SROWS (TH + 8)        // 40 staged sheared rows
#define SCOLS (W_ + 8)        // 264 staged cols; LDS = 41.25 KiB
#define NPB 1024              // blocks per conv; each block does 2 vertical tiles
#define PSTRIDE 260           // padded row stride (floats); right-pad==next left-pad
#define PPLANE (H_ * PSTRIDE)

// 4-byte-aligned float4 view (shear loads are dword- but not 16B-aligned).
struct alignas(4) f4u { float x, y, z, w; };

// staged registers for one tile: 2 loads (padded) or 5 scalars (unpadded) per row
struct SRegs { f4u a[10]; float e[10]; };

struct Factors { float A0, A2, A4, A6, A8, B1, B3, B5, B7, vc[9]; };

template<bool SRC_PAD>
static __device__ __forceinline__ void stage_issue(
    const float* __restrict__ base, int h0, int off, int sign,
    int lane, int wave, SRegs& R)
{
    #pragma unroll
    for (int u = 0; u < 10; ++u) {
        const int hr = h0 + wave + u * 4 - 4;
        if ((unsigned)hr < 256u) {                   // wave-coherent
            if (SRC_PAD) {
                const float* row = base + (size_t)hr * PSTRIDE;
                const int d  = off + sign * hr + 4 + lane * 4;   // c0+4
                const int dc = min(max(d, 0), 259);
                R.a[u] = *(const f4u*)(row + dc);
                R.e[u] = row[dc + 4];                            // <= row+263, legal
            } else {
                const float* row = base + (size_t)hr * W_;
                const int c0 = off + sign * hr + lane * 4;
                R.a[u].x = row[min(max(c0,     0), 255)];
                R.a[u].y = row[min(max(c0 + 1, 0), 255)];
                R.a[u].z = row[min(max(c0 + 2, 0), 255)];
                R.a[u].w = row[min(max(c0 + 3, 0), 255)];
                R.e[u]   = row[min(max(c0 + 4, 0), 255)];
            }
        }
    }
}

template<bool SRC_PAD>
static __device__ __forceinline__ void stage_write(
    int h0, int off, int sign, int lane, int wave,
    const SRegs& R, float (&s_sh)[SROWS][SCOLS])
{
    #pragma unroll
    for (int u = 0; u < 10; ++u) {
        const int r  = wave + u * 4;
        const int hr = h0 + r - 4;
        float4 v = make_float4(0.f, 0.f, 0.f, 0.f);
        if ((unsigned)hr < 256u) {
            if (SRC_PAD) {
                const int d = off + sign * hr + 4 + lane * 4;
                const bool valid = (unsigned)d < 260u;           // c0 in [-4,255]
                v.x = valid ? 0.5f * (R.a[u].x + R.a[u].y) : 0.f;
                v.y = valid ? 0.5f * (R.a[u].y + R.a[u].z) : 0.f;
                v.z = valid ? 0.5f * (R.a[u].z + R.a[u].w) : 0.f;
                v.w = valid ? 0.5f * (R.a[u].w + R.e[u])   : 0.f;
            } else {
                const int c0 = off + sign * hr + lane * 4;
                const float t0 = ((unsigned)c0       < 256u) ? R.a[u].x : 0.f;
                const float t1 = ((unsigned)(c0 + 1) < 256u) ? R.a[u].y : 0.f;
                const float t2 = ((unsigned)(c0 + 2) < 256u) ? R.a[u].z : 0.f;
                const float t3 = ((unsigned)(c0 + 3) < 256u) ? R.a[u].w : 0.f;
                const float t4 = ((unsigned)(c0 + 4) < 256u) ? R.e[u]   : 0.f;
                v.x = 0.5f * (t0 + t1);
                v.y = 0.5f * (t1 + t2);
                v.z = 0.5f * (t2 + t3);
                v.w = 0.5f * (t3 + t4);
            }
        }
        *(float4*)&s_sh[r][4 + lane * 4] = v;        // 16B-aligned
    }
}

template<bool DST_PAD>
static __device__ __forceinline__ void compute_store(
    float (&s_sh)[SROWS][SCOLS], float* __restrict__ dst, const Factors& F,
    int plane_idx, int c, int h0, bool first_pad)
{
    const int tid  = threadIdx.x;
    const int rg   = tid >> 6;           // 0..3 -> out rows rg*8 .. rg*8+7
    const int lane = tid & 63;
    const int w0   = lane * 4;

    float acc[8][4];
    #pragma unroll
    for (int i = 0; i < 8; ++i)
        #pragma unroll
        for (int j = 0; j < 4; ++j) acc[i][j] = 0.f;

    __builtin_amdgcn_s_setprio(1);
    #pragma unroll
    for (int t = 0; t < 16; ++t) {       // staged rows rg*8 + t
        const int rr = rg * 8 + t;
        const float4 sa  = *(const float4*)&s_sh[rr][w0];
        const float4 sb  = *(const float4*)&s_sh[rr][w0 + 4];
        const float4 sc4 = *(const float4*)&s_sh[rr][w0 + 8];
        const float s[12] = {sa.x, sa.y, sa.z, sa.w,
                             sb.x, sb.y, sb.z, sb.w,
                             sc4.x, sc4.y, sc4.z, sc4.w};
        float ha[4], hb[4];
        #pragma unroll
        for (int j = 0; j < 4; ++j) {
            ha[j] = fmaf(F.A8, s[j + 8],
                    fmaf(F.A6, s[j + 6],
                    fmaf(F.A4, s[j + 4],
                    fmaf(F.A2, s[j + 2], F.A0 * s[j]))));
            hb[j] = fmaf(F.B7, s[j + 7],
                    fmaf(F.B5, s[j + 5],
                    fmaf(F.B3, s[j + 3], F.B1 * s[j + 1])));
        }
        #pragma unroll
        for (int i = 0; i < 8; ++i) {
            const int ky = t - i;        // compile-time after unroll
            if (ky >= 0 && ky < 9) {
                #pragma unroll
                for (int j = 0; j < 4; ++j) {
                    const float hv = (ky & 1) ? hb[j] : ha[j];
                    acc[i][j] = fmaf(F.vc[ky], hv, acc[i][j]);
                }
            }
        }
    }
    __builtin_amdgcn_s_setprio(0);

    // channel-0 delta: += sheared image value at the output location
    if (c == 0) {
        #pragma unroll
        for (int i = 0; i < 8; ++i) {
            const float4 sv = *(const float4*)&s_sh[rg * 8 + i + 4][w0 + 4];
            acc[i][0] += sv.x; acc[i][1] += sv.y; acc[i][2] += sv.z; acc[i][3] += sv.w;
        }
    }

    if (DST_PAD) {
        float* plane = dst + (size_t)plane_idx * PPLANE;
        // halo: zero right-pad of each owned row == left-pad of next row
        if (lane < 8)
            *(float4*)(plane + (size_t)(h0 + rg * 8 + lane + 1) * PSTRIDE) =
                make_float4(0.f, 0.f, 0.f, 0.f);
        if (first_pad && tid == 8)       // very first plane's row-0 left pad
            *(float4*)dst = make_float4(0.f, 0.f, 0.f, 0.f);
        float* optr = plane + (size_t)(h0 + rg * 8) * PSTRIDE + 4 + w0;
        #pragma unroll
        for (int i = 0; i < 8; ++i) {
            const float4 v = {acc[i][0], acc[i][1], acc[i][2], acc[i][3]};
            *(float4*)(optr + (size_t)i * PSTRIDE) = v;  // 16B-aligned
        }
    } else {
        float* optr = dst + (((size_t)plane_idx) * H_ + h0 + rg * 8) * (size_t)W_ + w0;
        #pragma unroll
        for (int i = 0; i < 8; ++i) {
            const float4 v = {acc[i][0], acc[i][1], acc[i][2], acc[i][3]};
            *(float4*)(optr + (size_t)i * W_) = v;
        }
    }
}

template<bool SP, bool DP>
__global__ __launch_bounds__(256, 3) void shear_sepconv_kernel(
    const float* __restrict__ in, float* __restrict__ dst,
    const float* __restrict__ filt, int parity)
{
    __shared__ float s_sh[SROWS][SCOLS];

    const int tid  = threadIdx.x;
    const int bid  = (int)blockIdx.x;
    const int pr   = bid & 3;            // vertical pair: rows [pr*64, pr*64+64)
    const int c    = (bid >> 2) & 63;    // C = 64
    const int b    = bid >> 8;
    const int h0   = pr * 64;            // tile0; tile1 = h0 + 32
    const int sign = parity ? -1 : 1;
    const int off  = parity ? 127 : -128;
    const int wave = tid >> 6;
    const int lane = tid & 63;

    const int plane_idx = b * C_ + c;
    const float* base = in + (size_t)plane_idx * (size_t)(SP ? PPLANE : H_ * W_);

    // LDS halo cols [0,4) and [260,264): always zero, written once, never touched
    // by stage_write -> valid for both tiles.
    if (tid < 80) {
        const int r = tid >> 1;
        *(float4*)&s_sh[r][(tid & 1) ? 260 : 0] = make_float4(0.f, 0.f, 0.f, 0.f);
    }

    // ---- pipeline: stage0 | issue1 | bar | compute0 | bar | write1 | bar | compute1
    SRegs R0;
    stage_issue<SP>(base, h0, off, sign, lane, wave, R0);
    stage_write<SP>(h0, off, sign, lane, wave, R0, s_sh);
    SRegs R1;
    stage_issue<SP>(base, h0 + TH, off, sign, lane, wave, R1);  // hides under compute0
    __builtin_amdgcn_sched_barrier(0);   // pin: tile1 loads issue before compute0

    // separable factors from channel 1 (uniform; identical for all c)
    const float* f1 = filt + 81;
    Factors F;
    F.A4 = sqrtf(fmaxf(-f1[4 * 9 + 4], 0.f));
    const float rA4 = 1.f / F.A4;
    F.A0 = -f1[0 * 9 + 4] * rA4;
    F.A2 = -f1[2 * 9 + 4] * rA4;
    F.A6 = -f1[6 * 9 + 4] * rA4;
    F.A8 = -f1[8 * 9 + 4] * rA4;
    F.B5 = sqrtf(fmaxf(f1[5 * 9 + 5], 0.f));
    const float rB5 = 1.f / F.B5;
    F.B1 = f1[1 * 9 + 5] * rB5;
    F.B3 = f1[3 * 9 + 5] * rB5;
    F.B7 = f1[7 * 9 + 5] * rB5;
    F.vc[0] = -F.A0; F.vc[1] = F.B1; F.vc[2] = -F.A2; F.vc[3] = F.B3;
    F.vc[4] = -F.A4; F.vc[5] = F.B5; F.vc[6] = -F.A6; F.vc[7] = F.B7;
    F.vc[8] = -F.A8;

    __syncthreads();
    compute_store<DP>(s_sh, dst, F, plane_idx, c, h0, bid == 0);
    __syncthreads();                     // all s_sh reads of tile0 done
    stage_write<SP>(h0 + TH, off, sign, lane, wave, R1, s_sh);
    __syncthreads();
    compute_store<DP>(s_sh, dst, F, plane_idx, c, h0 + TH, false);
}

extern "C" void kernel_launch(void* const* d_in, const int* in_sizes, int n_in,
                              void* d_out, int out_size, void* d_ws, size_t ws_size,
                              hipStream_t stream) {
    const float* x    = (const float*)d_in[0];
    const float* filt = (const float*)d_in[1];
    float* out = (float*)d_out;
    float* wsb = (float*)d_ws;          // 64 MiB spare
    const size_t N = (size_t)B_ * C_ * H_ * W_;   // floats per 64MiB slot

    float* S[8];
    for (int k = 0; k < 8; ++k) S[k] = out + (size_t)k * N;

    // Padded scratch regions inside out (66MiB spacing; padded buf = 65.01MiB).
    // Liveness verified in R6 (same launch set): no launch reads what any
    // in-flight launch writes; no final overwritten after being written.
    float* RB  = out;                                   // [  0, 66) MiB
    float* RBA = out + ((size_t)66 << 20) / 4;          // [ 66,132) MiB
    float* RA  = out + ((size_t)132 << 20) / 4;         // [132,198) MiB
    float* ABs = out;                                   // [  0, 64) MiB, after RB dead

    const dim3 grid(NPB);
    const dim3 block(256);

    #define L(SP, DP, src, dst, par) \
        shear_sepconv_kernel<SP, DP><<<grid, block, 0, stream>>>(src, dst, filt, par)

    // Phase 1: B-subtree (finals out4..7 in [256,512)MiB, disjoint from scratch)
    L(false, true , x,   RB,   1);   // B  = shear(-1) conv, padded
    L(true , true , RB,  RBA,  0);   // BA, padded
    L(true , false, RBA, S[4], 0);   // out4
    L(true , false, RBA, S[5], 1);   // out5
    L(true , true , RB,  RBA,  1);   // BB, padded (BA dead)
    L(true , false, RBA, S[6], 0);   // out6
    L(true , false, RBA, S[7], 1);   // out7
    // Phase 2: A-subtree (RB/RBA dead; RA overlaps out2/3 slots, dead before writes)
    L(false, true , x,   RA,   0);   // A, padded
    L(true , false, RA,  wsb,  0);   // AA, unpadded -> ws
    L(true , false, RA,  ABs,  1);   // AB, unpadded -> [0,64)MiB (RB dead)
    L(false, false, ABs, S[2], 0);   // out2 (masked read)
    L(false, false, ABs, S[3], 1);   // out3
    L(false, false, wsb, S[0], 0);   // out0 (overwrites ABs, dead)
    L(false, false, wsb, S[1], 1);   // out1
    #undef L
}

// Round 9
// 394.028 us; speedup vs baseline: 2.1302x; 2.1302x over previous
//
#include <hip/hip_runtime.h>
#include <hip/hip_fp16.h>

// DirectionalFilterBank: 3-level binary tree of (shear ±1 -> depthwise 9x9 conv).
// shear(x,s)[h,w] = 0.5*(x[h,c0]+x[h,c0+1]), c0 = w + s*h + (s>0 ? -128 : 127),
// w in [0,256); conv zero-pads the SHEARED image by 4. Filter rank-2 separable:
// filt_c = -(A (x) A) + (B (x) B) [+ center delta, c==0].
//
// History: R6 best = 488us (fp32 padded intermediates). R7/R8 overlap experiments
// failed -> phase-lock theory dead. Eliminated: issue (floor 9us), LDS (2us), L2
// (14%), occupancy (R2/R3), launch overhead (R4), phase-lock (R4/R8). Remaining
// suspect: L3-path mixed R/W bandwidth (~4.6 TB/s of ~5ish achievable).
//
// THIS ROUND (discriminator + probable win): FP16 INTERMEDIATES (finals fp32).
// All 6 tree intermediates stored fp16, padded stride 260 halves (right-pad ==
// next row's left pad; chain across planes; producers zero their own pads).
// Traffic 1.85 -> 1.26 GB (-32%). Staging: one 4B-aligned 16B window (8 halves),
// even/odd select, avg -> LDS stays FP32; compute loop unchanged. Writes pack
// via __floats2half2_rn. Instr +~10%: if instr-bound -> +3%, if mem-bound -> -25%.
//
// 14-launch schedule, fp16 regions inside final slots (all verified disjoint):
//  L1  x  ->Bh(S0)   L2 Bh->BAh(S2)   L3 BAh->out4(S4)  L4 BAh->out5(S5)
//  L5  Bh ->BBh(S3)  L6 BBh->out6(S6) L7 BBh->out7(S7)  L8 x->Ah(S1)
//  L9  Ah ->AAh(S2: BA dead)          L10 Ah->ABh(ws)
//  L11 AAh->out0(S0: B dead)          L12 AAh->out1(S1: A dead)
//  L13 ABh->out2(S2: AA dead)         L14 ABh->out3(S3: BB dead)
// Finals each written once, never read/overwritten after. fp16 plane = 32.5MiB
// per 64MiB slot; all over-reads (<=10B past plane) land in slot slack.

#define B_ 4
#define C_ 64
#define H_ 256
#define W_ 256
#define TH 32                 // output rows per block
#define SROWS (TH + 8)        // 40 staged sheared rows
#define SCOLS (W_ + 8)        // 264 staged cols; LDS = 41.25 KiB (fp32)
#define NPB 2048              // blocks per conv = 4*64*8
#define PSTRIDE 260           // padded row stride in HALVES
#define PPLANE (H_ * PSTRIDE) // halves per padded plane (66560; 133120 B)

struct alignas(4) h8 { unsigned int u[4]; };   // 8 halves, 4B-aligned 16B load

// SRC_H: source is fp16-padded intermediate; else fp32 unpadded (x).
// DST_H: dest is fp16-padded intermediate; else fp32 final.
template<bool SRC_H, bool DST_H>
__global__ __launch_bounds__(256) void shear_sepconv_kernel(
    const void* __restrict__ in_, void* __restrict__ dst_,
    const float* __restrict__ filt, int parity)
{
    __shared__ float s_sh[SROWS][SCOLS];

    const int tid  = threadIdx.x;
    const int bid  = (int)blockIdx.x;
    const int tile = bid & 7;            // H/TH = 8
    const int c    = (bid >> 3) & 63;    // C = 64
    const int b    = bid >> 9;
    const int h0   = tile * TH;
    const int sign = parity ? -1 : 1;
    const int off  = parity ? 127 : -128;

    const int plane_idx = b * C_ + c;

    // ---- stage sheared rows h0-4 .. h0+35 (wave w: rows w+4u, lane: 4 cols) ----
    {
        const int wave = tid >> 6;
        const int lane = tid & 63;

        // LDS halo cols [0,4) and [260,264) are always zero (conv pads the
        // SHEARED image; sh(w'<0 or >=256) == 0 by definition)
        if (tid < 80) {
            const int r = tid >> 1;
            *(float4*)&s_sh[r][(tid & 1) ? 260 : 0] = make_float4(0.f, 0.f, 0.f, 0.f);
        }

        #pragma unroll
        for (int u = 0; u < 10; ++u) {
            const int r  = wave + u * 4;
            const int hr = h0 + r - 4;
            float4 v = make_float4(0.f, 0.f, 0.f, 0.f);
            if ((unsigned)hr < 256u) {                   // wave-coherent
                if (SRC_H) {
                    // fp16 padded: p[j] = y(hr, j-4), j in [0,260); j in [260,264)
                    // overflows into next row/plane pad == 0 (producers write it).
                    const __half* rowh = (const __half*)in_
                        + (size_t)plane_idx * PPLANE + (size_t)hr * PSTRIDE;
                    const int d  = off + sign * hr + 4 + lane * 4;  // first half idx
                    const int m  = d & ~1;
                    const int mc = min(max(m, 0), 258);
                    const bool qhi   = (d & 1) != 0;
                    const bool valid = (unsigned)d < 260u;          // c0 in [-4,255]
                    union { h8 raw; __half2 h2[4]; } U;
                    U.raw = *(const h8*)(rowh + mc);                // 4B-aligned 16B
                    const float2 g01 = __half22float2(U.h2[0]);     // h0,h1
                    const float2 g23 = __half22float2(U.h2[1]);     // h2,h3
                    const float2 g45 = __half22float2(U.h2[2]);     // h4,h5
                    const float t0 = qhi ? g01.y : g01.x;
                    const float t1 = qhi ? g23.x : g01.y;
                    const float t2 = qhi ? g23.y : g23.x;
                    const float t3 = qhi ? g45.x : g23.y;
                    const float t4 = qhi ? g45.y : g45.x;
                    v.x = valid ? 0.5f * (t0 + t1) : 0.f;
                    v.y = valid ? 0.5f * (t1 + t2) : 0.f;
                    v.z = valid ? 0.5f * (t2 + t3) : 0.f;
                    v.w = valid ? 0.5f * (t3 + t4) : 0.f;
                } else {
                    // fp32 unpadded (x): branchless clamp + per-element zero masks
                    const float* row = (const float*)in_
                        + (size_t)plane_idx * (H_ * W_) + (size_t)hr * W_;
                    const int c0 = off + sign * hr + lane * 4;
                    const int i0 = min(max(c0,     0), 255);
                    const int i1 = min(max(c0 + 1, 0), 255);
                    const int i2 = min(max(c0 + 2, 0), 255);
                    const int i3 = min(max(c0 + 3, 0), 255);
                    const int i4 = min(max(c0 + 4, 0), 255);
                    float t0 = row[i0];
                    float t1 = row[i1];
                    float t2 = row[i2];
                    float t3 = row[i3];
                    float t4 = row[i4];
                    t0 = ((unsigned)c0       < 256u) ? t0 : 0.f;
                    t1 = ((unsigned)(c0 + 1) < 256u) ? t1 : 0.f;
                    t2 = ((unsigned)(c0 + 2) < 256u) ? t2 : 0.f;
                    t3 = ((unsigned)(c0 + 3) < 256u) ? t3 : 0.f;
                    t4 = ((unsigned)(c0 + 4) < 256u) ? t4 : 0.f;
                    v.x = 0.5f * (t0 + t1);
                    v.y = 0.5f * (t1 + t2);
                    v.z = 0.5f * (t2 + t3);
                    v.w = 0.5f * (t3 + t4);
                }
            }
            *(float4*)&s_sh[r][4 + lane * 4] = v;        // 16B-aligned
        }
    }

    // ---- separable factors from channel 1 (uniform; identical for all c) ----
    const float* f1 = filt + 81;
    const float A4  = sqrtf(fmaxf(-f1[4 * 9 + 4], 0.f));
    const float rA4 = 1.f / A4;
    const float A0  = -f1[0 * 9 + 4] * rA4;
    const float A2  = -f1[2 * 9 + 4] * rA4;
    const float A6  = -f1[6 * 9 + 4] * rA4;
    const float A8  = -f1[8 * 9 + 4] * rA4;
    const float B5  = sqrtf(fmaxf(f1[5 * 9 + 5], 0.f));
    const float rB5 = 1.f / B5;
    const float B1  = f1[1 * 9 + 5] * rB5;
    const float B3  = f1[3 * 9 + 5] * rB5;
    const float B7  = f1[7 * 9 + 5] * rB5;
    const float vc[9] = {-A0, B1, -A2, B3, -A4, B5, -A6, B7, -A8};

    __syncthreads();

    // ---- compute: 4 row-groups x 8 rows; thread = 4 cols x 8 rows (window 16) ----
    const int rg   = tid >> 6;           // 0..3 -> out rows rg*8 .. rg*8+7
    const int lane = tid & 63;
    const int w0   = lane * 4;

    float acc[8][4];
    #pragma unroll
    for (int i = 0; i < 8; ++i)
        #pragma unroll
        for (int j = 0; j < 4; ++j) acc[i][j] = 0.f;

    __builtin_amdgcn_s_setprio(1);
    #pragma unroll
    for (int t = 0; t < 16; ++t) {       // staged rows rg*8 + t
        const int rr = rg * 8 + t;
        const float4 sa  = *(const float4*)&s_sh[rr][w0];
        const float4 sb  = *(const float4*)&s_sh[rr][w0 + 4];
        const float4 sc4 = *(const float4*)&s_sh[rr][w0 + 8];
        const float s[12] = {sa.x, sa.y, sa.z, sa.w,
                             sb.x, sb.y, sb.z, sb.w,
                             sc4.x, sc4.y, sc4.z, sc4.w};
        float ha[4], hb[4];
        #pragma unroll
        for (int j = 0; j < 4; ++j) {
            ha[j] = fmaf(A8, s[j + 8],
                    fmaf(A6, s[j + 6],
                    fmaf(A4, s[j + 4],
                    fmaf(A2, s[j + 2], A0 * s[j]))));
            hb[j] = fmaf(B7, s[j + 7],
                    fmaf(B5, s[j + 5],
                    fmaf(B3, s[j + 3], B1 * s[j + 1])));
        }
        #pragma unroll
        for (int i = 0; i < 8; ++i) {
            const int ky = t - i;        // compile-time after unroll
            if (ky >= 0 && ky < 9) {
                #pragma unroll
                for (int j = 0; j < 4; ++j) {
                    const float hv = (ky & 1) ? hb[j] : ha[j];
                    acc[i][j] = fmaf(vc[ky], hv, acc[i][j]);
                }
            }
        }
    }
    __builtin_amdgcn_s_setprio(0);

    // channel-0 delta: += sheared image value at the output location
    if (c == 0) {
        #pragma unroll
        for (int i = 0; i < 8; ++i) {
            const float4 sv = *(const float4*)&s_sh[rg * 8 + i + 4][w0 + 4];
            acc[i][0] += sv.x; acc[i][1] += sv.y; acc[i][2] += sv.z; acc[i][3] += sv.w;
        }
    }

    if (DST_H) {
        __half* plane = (__half*)dst_ + (size_t)plane_idx * PPLANE;
        // zero next-row left-pad (4 halves = 8B). Row r's reader sees row (r-1)'s
        // write; chains across planes; row 256 write lands in slot slack.
        if (lane < 8) {
            uint2 z; z.x = 0u; z.y = 0u;
            *(uint2*)(plane + (size_t)(h0 + rg * 8 + lane + 1) * PSTRIDE) = z;
        }
        if (bid == 0 && tid == 8) {      // very first plane's row-0 left pad
            uint2 z; z.x = 0u; z.y = 0u;
            *(uint2*)dst_ = z;
        }
        __half* optr = plane + (size_t)(h0 + rg * 8) * PSTRIDE + 4 + w0;
        #pragma unroll
        for (int i = 0; i < 8; ++i) {
            union { __half2 h2; unsigned int u; } p0, p1;
            p0.h2 = __floats2half2_rn(acc[i][0], acc[i][1]);
            p1.h2 = __floats2half2_rn(acc[i][2], acc[i][3]);
            uint2 pk; pk.x = p0.u; pk.y = p1.u;
            *(uint2*)(optr + (size_t)i * PSTRIDE) = pk;   // 8B-aligned
        }
    } else {
        float* optr = (float*)dst_
            + (((size_t)plane_idx) * H_ + h0 + rg * 8) * (size_t)W_ + w0;
        #pragma unroll
        for (int i = 0; i < 8; ++i) {
            const float4 v = {acc[i][0], acc[i][1], acc[i][2], acc[i][3]};
            *(float4*)(optr + (size_t)i * W_) = v;
        }
    }
}

extern "C" void kernel_launch(void* const* d_in, const int* in_sizes, int n_in,
                              void* d_out, int out_size, void* d_ws, size_t ws_size,
                              hipStream_t stream) {
    const float* x    = (const float*)d_in[0];
    const float* filt = (const float*)d_in[1];
    float* out = (float*)d_out;
    void*  wsb = d_ws;                  // 64 MiB spare: ABh lives here
    const size_t N = (size_t)B_ * C_ * H_ * W_;   // floats per 64MiB slot

    float* S[8];
    for (int k = 0; k < 8; ++k) S[k] = out + (size_t)k * N;

    // fp16 padded intermediates inside final slots (32.5 MiB per 64 MiB slot)
    void* Bh  = (void*)S[0];
    void* BAh = (void*)S[2];
    void* BBh = (void*)S[3];
    void* Ah  = (void*)S[1];
    void* AAh = (void*)S[2];            // reused after BA dead
    void* ABh = wsb;

    const dim3 grid(NPB);
    const dim3 block(256);

    #define L(SH, DH, src, dst, par) \
        shear_sepconv_kernel<SH, DH><<<grid, block, 0, stream>>>(src, dst, filt, par)

    // B-subtree
    L(false, true , x,   Bh,   1);   // L1  B
    L(true , true , Bh,  BAh,  0);   // L2  BA
    L(true , false, BAh, S[4], 0);   // L3  out4
    L(true , false, BAh, S[5], 1);   // L4  out5
    L(true , true , Bh,  BBh,  1);   // L5  BB (BA slots disjoint)
    L(true , false, BBh, S[6], 0);   // L6  out6
    L(true , false, BBh, S[7], 1);   // L7  out7
    // A-subtree
    L(false, true , x,   Ah,   0);   // L8  A
    L(true , true , Ah,  AAh,  0);   // L9  AA (S2: BA dead)
    L(true , true , Ah,  ABh,  1);   // L10 AB -> ws
    L(true , false, AAh, S[0], 0);   // L11 out0 (S0: B dead)
    L(true , false, AAh, S[1], 1);   // L12 out1 (S1: A dead)
    L(true , false, ABh, S[2], 0);   // L13 out2 (S2: AA dead)
    L(true , false, ABh, S[3], 1);   // L14 out3 (S3: BB dead)
    #undef L
}

// Round 10
// 385.691 us; speedup vs baseline: 2.1763x; 1.0216x over previous
//
#include <hip/hip_runtime.h>
#include <hip/hip_fp16.h>

// DirectionalFilterBank: 3-level binary tree of (shear ±1 -> depthwise 9x9 conv).
// shear(x,s)[h,w] = 0.5*(x[h,c0]+x[h,c0+1]), c0 = w + s*h + (s>0 ? -128 : 127).
// Filter rank-2 separable: filt_c = -(A (x) A) + (B (x) B) [+ center delta, c==0].
//
// Cost model (validated R6->R9): time = traffic/6.3TB/s + ~194us fixed, ADDITIVE
// -> memory and compute phases don't overlap (in-order waves, phase-locked blocks).
// R9 = 394us (fp16 intermediates, traffic 1.26GB). THIS ROUND: break additivity.
// R8's overlap attempt spilled (fp32 staging regs + launch_bounds cap = 170-reg
// cliff). Now: fp16 sources need only 40 VGPR for a full tile's staged loads.
// Pipelined kernel (the 12 fp16-source convs; x-source convs keep R9 path):
//   2 vertical tiles/block: stage0->LDS | issue tile1 loads->regs |
//   sched_barrier | bar | compute0 (loads fly under FMA) | bar | write1 | bar
//   | compute1.  Peak ~150 VGPR < 170 -> 3 blocks/CU kept. Same LDS buffer.
// Arithmetic identical to R9 (reordered only) -> absmax unchanged.

#define B_ 4
#define C_ 64
#define H_ 256
#define W_ 256
#define TH 32                 // output rows per tile
#define SROWS (TH + 8)        // 40 staged sheared rows
#define SCOLS (W_ + 8)        // 264 staged cols; LDS = 41.25 KiB (fp32)
#define NPB 2048              // x-source kernel: 1 tile/block
#define NPB2 1024             // pipelined kernel: 2 tiles/block
#define PSTRIDE 260           // padded row stride in HALVES
#define PPLANE (H_ * PSTRIDE) // 66560 halves = 133120 B per plane

struct alignas(4) h8 { unsigned int u[4]; };   // 8 halves, 4B-aligned 16B load

struct Factors { float A0, A2, A4, A6, A8, B1, B3, B5, B7, vc[9]; };

static __device__ __forceinline__ Factors mk_factors(const float* __restrict__ filt)
{
    const float* f1 = filt + 81;           // channel 1: uniform for all c
    Factors F;
    F.A4 = sqrtf(fmaxf(-f1[4 * 9 + 4], 0.f));
    const float rA4 = 1.f / F.A4;
    F.A0 = -f1[0 * 9 + 4] * rA4;  F.A2 = -f1[2 * 9 + 4] * rA4;
    F.A6 = -f1[6 * 9 + 4] * rA4;  F.A8 = -f1[8 * 9 + 4] * rA4;
    F.B5 = sqrtf(fmaxf(f1[5 * 9 + 5], 0.f));
    const float rB5 = 1.f / F.B5;
    F.B1 = f1[1 * 9 + 5] * rB5;  F.B3 = f1[3 * 9 + 5] * rB5;
    F.B7 = f1[7 * 9 + 5] * rB5;
    F.vc[0] = -F.A0; F.vc[1] = F.B1; F.vc[2] = -F.A2; F.vc[3] = F.B3;
    F.vc[4] = -F.A4; F.vc[5] = F.B5; F.vc[6] = -F.A6; F.vc[7] = F.B7;
    F.vc[8] = -F.A8;
    return F;
}

// 16B fp16 window (8 halves starting at even index mc=clamp(d&~1)) -> sheared
// float4 for cols 4L..4L+3. d = first half index; pads guarantee correctness.
static __device__ __forceinline__ float4 shear_avg_h(const h8 raw, int d)
{
    union { h8 r; __half2 h2[4]; } U; U.r = raw;
    const bool qhi   = (d & 1) != 0;
    const bool valid = (unsigned)d < 260u;          // c0 in [-4,255]
    const float2 g01 = __half22float2(U.h2[0]);
    const float2 g23 = __half22float2(U.h2[1]);
    const float2 g45 = __half22float2(U.h2[2]);
    const float t0 = qhi ? g01.y : g01.x;
    const float t1 = qhi ? g23.x : g01.y;
    const float t2 = qhi ? g23.y : g23.x;
    const float t3 = qhi ? g45.x : g23.y;
    const float t4 = qhi ? g45.y : g45.x;
    float4 v;
    v.x = valid ? 0.5f * (t0 + t1) : 0.f;
    v.y = valid ? 0.5f * (t1 + t2) : 0.f;
    v.z = valid ? 0.5f * (t2 + t3) : 0.f;
    v.w = valid ? 0.5f * (t3 + t4) : 0.f;
    return v;
}

template<bool DST_H>
static __device__ __forceinline__ void compute_store(
    float (&s_sh)[SROWS][SCOLS], void* __restrict__ dst_, const Factors& F,
    int plane_idx, int c, int h0t, bool first_pad)
{
    const int tid  = threadIdx.x;
    const int rg   = tid >> 6;           // 0..3 -> out rows rg*8 .. rg*8+7
    const int lane = tid & 63;
    const int w0   = lane * 4;

    float acc[8][4];
    #pragma unroll
    for (int i = 0; i < 8; ++i)
        #pragma unroll
        for (int j = 0; j < 4; ++j) acc[i][j] = 0.f;

    __builtin_amdgcn_s_setprio(1);
    #pragma unroll
    for (int t = 0; t < 16; ++t) {       // staged rows rg*8 + t
        const int rr = rg * 8 + t;
        const float4 sa  = *(const float4*)&s_sh[rr][w0];
        const float4 sb  = *(const float4*)&s_sh[rr][w0 + 4];
        const float4 sc4 = *(const float4*)&s_sh[rr][w0 + 8];
        const float s[12] = {sa.x, sa.y, sa.z, sa.w,
                             sb.x, sb.y, sb.z, sb.w,
                             sc4.x, sc4.y, sc4.z, sc4.w};
        float ha[4], hb[4];
        #pragma unroll
        for (int j = 0; j < 4; ++j) {
            ha[j] = fmaf(F.A8, s[j + 8],
                    fmaf(F.A6, s[j + 6],
                    fmaf(F.A4, s[j + 4],
                    fmaf(F.A2, s[j + 2], F.A0 * s[j]))));
            hb[j] = fmaf(F.B7, s[j + 7],
                    fmaf(F.B5, s[j + 5],
                    fmaf(F.B3, s[j + 3], F.B1 * s[j + 1])));
        }
        #pragma unroll
        for (int i = 0; i < 8; ++i) {
            const int ky = t - i;        // compile-time after unroll
            if (ky >= 0 && ky < 9) {
                #pragma unroll
                for (int j = 0; j < 4; ++j) {
                    const float hv = (ky & 1) ? hb[j] : ha[j];
                    acc[i][j] = fmaf(F.vc[ky], hv, acc[i][j]);
                }
            }
        }
    }
    __builtin_amdgcn_s_setprio(0);

    // channel-0 delta: += sheared image value at the output location
    if (c == 0) {
        #pragma unroll
        for (int i = 0; i < 8; ++i) {
            const float4 sv = *(const float4*)&s_sh[rg * 8 + i + 4][w0 + 4];
            acc[i][0] += sv.x; acc[i][1] += sv.y; acc[i][2] += sv.z; acc[i][3] += sv.w;
        }
    }

    if (DST_H) {
        __half* plane = (__half*)dst_ + (size_t)plane_idx * PPLANE;
        // zero next-row left-pad (4 halves = 8B); chains across rows/planes
        if (lane < 8) {
            uint2 z; z.x = 0u; z.y = 0u;
            *(uint2*)(plane + (size_t)(h0t + rg * 8 + lane + 1) * PSTRIDE) = z;
        }
        if (first_pad && tid == 8) {     // very first plane's row-0 left pad
            uint2 z; z.x = 0u; z.y = 0u;
            *(uint2*)dst_ = z;
        }
        __half* optr = plane + (size_t)(h0t + rg * 8) * PSTRIDE + 4 + (lane * 4);
        #pragma unroll
        for (int i = 0; i < 8; ++i) {
            union { __half2 h2; unsigned int u; } p0, p1;
            p0.h2 = __floats2half2_rn(acc[i][0], acc[i][1]);
            p1.h2 = __floats2half2_rn(acc[i][2], acc[i][3]);
            uint2 pk; pk.x = p0.u; pk.y = p1.u;
            *(uint2*)(optr + (size_t)i * PSTRIDE) = pk;   // 8B-aligned
        }
    } else {
        float* optr = (float*)dst_
            + (((size_t)plane_idx) * H_ + h0t + rg * 8) * (size_t)W_ + w0;
        #pragma unroll
        for (int i = 0; i < 8; ++i) {
            const float4 v = {acc[i][0], acc[i][1], acc[i][2], acc[i][3]};
            *(float4*)(optr + (size_t)i * W_) = v;
        }
    }
}

// ---------- pipelined kernel: fp16 padded source, 2 vertical tiles/block ----------
template<bool DST_H>
__global__ __launch_bounds__(256) void shear_pipe_kernel(
    const void* __restrict__ in_, void* __restrict__ dst_,
    const float* __restrict__ filt, int parity)
{
    __shared__ float s_sh[SROWS][SCOLS];

    const int tid  = threadIdx.x;
    const int bid  = (int)blockIdx.x;
    const int pr   = bid & 3;            // vertical pair: tiles pr*64, pr*64+32
    const int c    = (bid >> 2) & 63;
    const int b    = bid >> 8;
    const int h0   = pr * 64;
    const int sign = parity ? -1 : 1;
    const int off  = parity ? 127 : -128;
    const int wave = tid >> 6;
    const int lane = tid & 63;
    const int plane_idx = b * C_ + c;
    const __half* src = (const __half*)in_ + (size_t)plane_idx * PPLANE;

    // LDS halo cols [0,4) and [260,264): zero once; staging never touches them
    if (tid < 80) {
        const int r = tid >> 1;
        *(float4*)&s_sh[r][(tid & 1) ? 260 : 0] = make_float4(0.f, 0.f, 0.f, 0.f);
    }

    // ---- stage tile0 (rows h0-4 .. h0+35): load + convert + LDS write ----
    #pragma unroll
    for (int u = 0; u < 10; ++u) {
        const int r  = wave + u * 4;
        const int hr = h0 + r - 4;
        float4 v = make_float4(0.f, 0.f, 0.f, 0.f);
        if ((unsigned)hr < 256u) {                       // wave-uniform
            const __half* rowh = src + (size_t)hr * PSTRIDE;
            const int d  = off + sign * hr + 4 + lane * 4;
            const int mc = min(max(d & ~1, 0), 258);
            const h8 raw = *(const h8*)(rowh + mc);      // 4B-aligned 16B
            v = shear_avg_h(raw, d);
        }
        *(float4*)&s_sh[r][4 + lane * 4] = v;            // 16B-aligned
    }

    // ---- issue tile1 loads (rows h0+28 .. h0+67) into registers (40 VGPR) ----
    h8 R[10] = {};
    #pragma unroll
    for (int u = 0; u < 10; ++u) {
        const int hr = h0 + 28 + wave + u * 4;           // (h0+32) + r - 4
        if ((unsigned)hr < 256u) {                       // wave-uniform
            const __half* rowh = src + (size_t)hr * PSTRIDE;
            const int d  = off + sign * hr + 4 + lane * 4;
            const int mc = min(max(d & ~1, 0), 258);
            R[u] = *(const h8*)(rowh + mc);
        }
    }
    __builtin_amdgcn_sched_barrier(0);   // pin: loads issued before compute0

    const Factors F = mk_factors(filt);

    __syncthreads();
    compute_store<DST_H>(s_sh, dst_, F, plane_idx, c, h0, bid == 0);
    __syncthreads();                     // tile0's s_sh reads done

    // ---- write tile1 (loads completed under compute0) ----
    #pragma unroll
    for (int u = 0; u < 10; ++u) {
        const int r  = wave + u * 4;
        const int hr = h0 + 28 + r;
        float4 v = make_float4(0.f, 0.f, 0.f, 0.f);
        if ((unsigned)hr < 256u) {
            const int d = off + sign * hr + 4 + lane * 4;
            v = shear_avg_h(R[u], d);
        }
        *(float4*)&s_sh[r][4 + lane * 4] = v;
    }
    __syncthreads();
    compute_store<DST_H>(s_sh, dst_, F, plane_idx, c, h0 + TH, false);
}

// ---------- x-source kernel (fp32 unpadded input), R9 path unchanged ----------
__global__ __launch_bounds__(256) void shear_x_kernel(
    const float* __restrict__ in, void* __restrict__ dst_,
    const float* __restrict__ filt, int parity)
{
    __shared__ float s_sh[SROWS][SCOLS];

    const int tid  = threadIdx.x;
    const int bid  = (int)blockIdx.x;
    const int tile = bid & 7;
    const int c    = (bid >> 3) & 63;
    const int b    = bid >> 9;
    const int h0   = tile * TH;
    const int sign = parity ? -1 : 1;
    const int off  = parity ? 127 : -128;
    const int plane_idx = b * C_ + c;

    {
        const int wave = tid >> 6;
        const int lane = tid & 63;

        if (tid < 80) {
            const int r = tid >> 1;
            *(float4*)&s_sh[r][(tid & 1) ? 260 : 0] = make_float4(0.f, 0.f, 0.f, 0.f);
        }

        #pragma unroll
        for (int u = 0; u < 10; ++u) {
            const int r  = wave + u * 4;
            const int hr = h0 + r - 4;
            float4 v = make_float4(0.f, 0.f, 0.f, 0.f);
            if ((unsigned)hr < 256u) {
                const float* row = in + (size_t)plane_idx * (H_ * W_)
                                      + (size_t)hr * W_;
                const int c0 = off + sign * hr + lane * 4;
                float t0 = row[min(max(c0,     0), 255)];
                float t1 = row[min(max(c0 + 1, 0), 255)];
                float t2 = row[min(max(c0 + 2, 0), 255)];
                float t3 = row[min(max(c0 + 3, 0), 255)];
                float t4 = row[min(max(c0 + 4, 0), 255)];
                t0 = ((unsigned)c0       < 256u) ? t0 : 0.f;
                t1 = ((unsigned)(c0 + 1) < 256u) ? t1 : 0.f;
                t2 = ((unsigned)(c0 + 2) < 256u) ? t2 : 0.f;
                t3 = ((unsigned)(c0 + 3) < 256u) ? t3 : 0.f;
                t4 = ((unsigned)(c0 + 4) < 256u) ? t4 : 0.f;
                v.x = 0.5f * (t0 + t1);
                v.y = 0.5f * (t1 + t2);
                v.z = 0.5f * (t2 + t3);
                v.w = 0.5f * (t3 + t4);
            }
            *(float4*)&s_sh[r][4 + lane * 4] = v;
        }
    }

    const Factors F = mk_factors(filt);
    __syncthreads();
    compute_store<true>(s_sh, dst_, F, plane_idx, c, h0, bid == 0);
}

extern "C" void kernel_launch(void* const* d_in, const int* in_sizes, int n_in,
                              void* d_out, int out_size, void* d_ws, size_t ws_size,
                              hipStream_t stream) {
    const float* x    = (const float*)d_in[0];
    const float* filt = (const float*)d_in[1];
    float* out = (float*)d_out;
    void*  wsb = d_ws;                  // 64 MiB spare: ABh lives here
    const size_t N = (size_t)B_ * C_ * H_ * W_;   // floats per 64MiB slot

    float* S[8];
    for (int k = 0; k < 8; ++k) S[k] = out + (size_t)k * N;

    // fp16 padded intermediates inside final slots (32.5 MiB per 64 MiB slot)
    // Schedule identical to R9 (liveness verified there):
    //  L1 x->Bh(S0)  L2 Bh->BAh(S2)  L3/L4 BAh->out4,5  L5 Bh->BBh(S3)
    //  L6/L7 BBh->out6,7  L8 x->Ah(S1)  L9 Ah->AAh(S2)  L10 Ah->ABh(ws)
    //  L11/12 AAh->out0,1  L13/14 ABh->out2,3
    void* Bh  = (void*)S[0];
    void* BAh = (void*)S[2];
    void* BBh = (void*)S[3];
    void* Ah  = (void*)S[1];
    void* AAh = (void*)S[2];            // reused after BA dead
    void* ABh = wsb;

    const dim3 block(256);
    const dim3 gridX(NPB);
    const dim3 gridP(NPB2);

    #define LX(src, dst, par) \
        shear_x_kernel<<<gridX, block, 0, stream>>>(src, dst, filt, par)
    #define LP(DH, src, dst, par) \
        shear_pipe_kernel<DH><<<gridP, block, 0, stream>>>(src, dst, filt, par)

    // B-subtree
    LX(x, Bh, 1);                        // L1  B
    LP(true , Bh,  BAh,  0);             // L2  BA
    LP(false, BAh, S[4], 0);             // L3  out4
    LP(false, BAh, S[5], 1);             // L4  out5
    LP(true , Bh,  BBh,  1);             // L5  BB
    LP(false, BBh, S[6], 0);             // L6  out6
    LP(false, BBh, S[7], 1);             // L7  out7
    // A-subtree
    LX(x, Ah, 0);                        // L8  A
    LP(true , Ah,  AAh,  0);             // L9  AA (S2: BA dead)
    LP(true , Ah,  ABh,  1);             // L10 AB -> ws
    LP(false, AAh, S[0], 0);             // L11 out0 (S0: B dead)
    LP(false, AAh, S[1], 1);             // L12 out1 (S1: A dead)
    LP(false, ABh, S[2], 0);             // L13 out2 (S2: AA dead)
    LP(false, ABh, S[3], 1);             // L14 out3 (S3: BB dead)
    #undef LX
    #undef LP
}

// Round 11
// 367.743 us; speedup vs baseline: 2.2825x; 1.0488x over previous
//
#include <hip/hip_runtime.h>
#include <hip/hip_fp16.h>

// DirectionalFilterBank: 3-level binary tree of (shear ±1 -> depthwise 9x9 conv).
// shear(x,s)[h,w] = 0.5*(x[h,c0]+x[h,c0+1]), c0 = w + s*h + (s>0 ? -128 : 127).
// Filter rank-2 separable: filt_c = -(A (x) A) + (B (x) B) [+ center delta, c==0].
//
// Cost model (validated R6-R10): time ~ traffic/6.3TB/s + instr component; only
// the traffic term moves reliably (R9: -0.59GB -> -94us; R10 overlap: -8us).
// R10 = 386us @ 1.25GB. THIS ROUND: kill the 2x intermediate read. Each
// intermediate is read twice (parity-0 and parity-1 children). Pair BOTH
// parities of one tile in one block using R10's proven pipeline shape:
//   stage p0 -> issue p1 loads to regs (SAME rows, other col window: L2-hot,
//   ~21KB/block, ~2MB/XCD < 4MB L2) -> compute p0 -> write p1 -> compute p1.
// R7 tried this pairing and lost because (a) fp32 footprint ~= L2 and
// (b) no prefetch; both fixed since R9/R10. Traffic 1252 -> 1048MB.
// x-source launches stay unpaired (fp32 staging regs would re-create R8 spill).
//
// 8-launch schedule (liveness: every read completes before its region is
// overwritten; finals written once, never touched after):
//  1 LX  x ->Bh(S0) p1        2 P  Bh ->BAh(S2),BBh(S3)
//  3 P  BAh->out4(S4),out5(S5) 4 P  BBh->out6(S6),out7(S7)
//  5 LX  x ->Ah(S1) p0        6 P  Ah ->AAh(S2:BA dead),ABh(ws)
//  7 P  AAh->out0(S0:B dead),out1(S1:A dead)
//  8 P  ABh->out2(S2:AA dead),out3(S3:BB dead)

#define B_ 4
#define C_ 64
#define H_ 256
#define W_ 256
#define TH 32                 // output rows per tile
#define SROWS (TH + 8)        // 40 staged sheared rows
#define SCOLS (W_ + 8)        // 264 staged cols; LDS = 41.25 KiB (fp32)
#define NPB 2048              // blocks per launch (x and pair kernels)
#define PSTRIDE 260           // padded row stride in HALVES
#define PPLANE (H_ * PSTRIDE) // 66560 halves = 133120 B per plane

struct alignas(4) h8 { unsigned int u[4]; };   // 8 halves, 4B-aligned 16B load

struct Factors { float A0, A2, A4, A6, A8, B1, B3, B5, B7, vc[9]; };

static __device__ __forceinline__ Factors mk_factors(const float* __restrict__ filt)
{
    const float* f1 = filt + 81;           // channel 1: uniform for all c
    Factors F;
    F.A4 = sqrtf(fmaxf(-f1[4 * 9 + 4], 0.f));
    const float rA4 = 1.f / F.A4;
    F.A0 = -f1[0 * 9 + 4] * rA4;  F.A2 = -f1[2 * 9 + 4] * rA4;
    F.A6 = -f1[6 * 9 + 4] * rA4;  F.A8 = -f1[8 * 9 + 4] * rA4;
    F.B5 = sqrtf(fmaxf(f1[5 * 9 + 5], 0.f));
    const float rB5 = 1.f / F.B5;
    F.B1 = f1[1 * 9 + 5] * rB5;  F.B3 = f1[3 * 9 + 5] * rB5;
    F.B7 = f1[7 * 9 + 5] * rB5;
    F.vc[0] = -F.A0; F.vc[1] = F.B1; F.vc[2] = -F.A2; F.vc[3] = F.B3;
    F.vc[4] = -F.A4; F.vc[5] = F.B5; F.vc[6] = -F.A6; F.vc[7] = F.B7;
    F.vc[8] = -F.A8;
    return F;
}

// 16B fp16 window (8 halves from even index mc=clamp(d&~1,0,258)) -> sheared
// float4 for cols 4L..4L+3. d = first half index; stored pads guarantee zeros.
static __device__ __forceinline__ float4 shear_avg_h(const h8 raw, int d)
{
    union { h8 r; __half2 h2[4]; } U; U.r = raw;
    const bool qhi   = (d & 1) != 0;
    const bool valid = (unsigned)d < 260u;          // c0 in [-4,255]
    const float2 g01 = __half22float2(U.h2[0]);
    const float2 g23 = __half22float2(U.h2[1]);
    const float2 g45 = __half22float2(U.h2[2]);
    const float t0 = qhi ? g01.y : g01.x;
    const float t1 = qhi ? g23.x : g01.y;
    const float t2 = qhi ? g23.y : g23.x;
    const float t3 = qhi ? g45.x : g23.y;
    const float t4 = qhi ? g45.y : g45.x;
    float4 v;
    v.x = valid ? 0.5f * (t0 + t1) : 0.f;
    v.y = valid ? 0.5f * (t1 + t2) : 0.f;
    v.z = valid ? 0.5f * (t2 + t3) : 0.f;
    v.w = valid ? 0.5f * (t3 + t4) : 0.f;
    return v;
}

template<bool DST_H>
static __device__ __forceinline__ void compute_store(
    float (&s_sh)[SROWS][SCOLS], void* __restrict__ dst_, const Factors& F,
    int plane_idx, int c, int h0t, bool first_pad)
{
    const int tid  = threadIdx.x;
    const int rg   = tid >> 6;           // 0..3 -> out rows rg*8 .. rg*8+7
    const int lane = tid & 63;
    const int w0   = lane * 4;

    float acc[8][4];
    #pragma unroll
    for (int i = 0; i < 8; ++i)
        #pragma unroll
        for (int j = 0; j < 4; ++j) acc[i][j] = 0.f;

    __builtin_amdgcn_s_setprio(1);
    #pragma unroll
    for (int t = 0; t < 16; ++t) {       // staged rows rg*8 + t
        const int rr = rg * 8 + t;
        const float4 sa  = *(const float4*)&s_sh[rr][w0];
        const float4 sb  = *(const float4*)&s_sh[rr][w0 + 4];
        const float4 sc4 = *(const float4*)&s_sh[rr][w0 + 8];
        const float s[12] = {sa.x, sa.y, sa.z, sa.w,
                             sb.x, sb.y, sb.z, sb.w,
                             sc4.x, sc4.y, sc4.z, sc4.w};
        float ha[4], hb[4];
        #pragma unroll
        for (int j = 0; j < 4; ++j) {
            ha[j] = fmaf(F.A8, s[j + 8],
                    fmaf(F.A6, s[j + 6],
                    fmaf(F.A4, s[j + 4],
                    fmaf(F.A2, s[j + 2], F.A0 * s[j]))));
            hb[j] = fmaf(F.B7, s[j + 7],
                    fmaf(F.B5, s[j + 5],
                    fmaf(F.B3, s[j + 3], F.B1 * s[j + 1])));
        }
        #pragma unroll
        for (int i = 0; i < 8; ++i) {
            const int ky = t - i;        // compile-time after unroll
            if (ky >= 0 && ky < 9) {
                #pragma unroll
                for (int j = 0; j < 4; ++j) {
                    const float hv = (ky & 1) ? hb[j] : ha[j];
                    acc[i][j] = fmaf(F.vc[ky], hv, acc[i][j]);
                }
            }
        }
    }
    __builtin_amdgcn_s_setprio(0);

    // channel-0 delta: += sheared image value at the output location
    if (c == 0) {
        #pragma unroll
        for (int i = 0; i < 8; ++i) {
            const float4 sv = *(const float4*)&s_sh[rg * 8 + i + 4][w0 + 4];
            acc[i][0] += sv.x; acc[i][1] += sv.y; acc[i][2] += sv.z; acc[i][3] += sv.w;
        }
    }

    if (DST_H) {
        __half* plane = (__half*)dst_ + (size_t)plane_idx * PPLANE;
        // zero next-row left-pad (4 halves = 8B); chains across rows/planes
        if (lane < 8) {
            uint2 z; z.x = 0u; z.y = 0u;
            *(uint2*)(plane + (size_t)(h0t + rg * 8 + lane + 1) * PSTRIDE) = z;
        }
        if (first_pad && tid == 8) {     // very first plane's row-0 left pad
            uint2 z; z.x = 0u; z.y = 0u;
            *(uint2*)dst_ = z;
        }
        __half* optr = plane + (size_t)(h0t + rg * 8) * PSTRIDE + 4 + (lane * 4);
        #pragma unroll
        for (int i = 0; i < 8; ++i) {
            union { __half2 h2; unsigned int u; } p0, p1;
            p0.h2 = __floats2half2_rn(acc[i][0], acc[i][1]);
            p1.h2 = __floats2half2_rn(acc[i][2], acc[i][3]);
            uint2 pk; pk.x = p0.u; pk.y = p1.u;
            *(uint2*)(optr + (size_t)i * PSTRIDE) = pk;   // 8B-aligned
        }
    } else {
        float* optr = (float*)dst_
            + (((size_t)plane_idx) * H_ + h0t + rg * 8) * (size_t)W_ + (lane * 4);
        #pragma unroll
        for (int i = 0; i < 8; ++i) {
            const float4 v = {acc[i][0], acc[i][1], acc[i][2], acc[i][3]};
            *(float4*)(optr + (size_t)i * W_) = v;
        }
    }
}

// ---- parity-pair kernel: fp16 padded source; one tile, BOTH parities ----
// p0: sign=+1 off=-128 -> dst0;  p1: sign=-1 off=127 -> dst1.
// p1's loads re-read the same rows p0 just pulled (L2-hot) and fly under
// compute0; source is fetched from L3/HBM once per block.
template<bool DST_H>
__global__ __launch_bounds__(256) void shear_pair_kernel(
    const void* __restrict__ in_, void* __restrict__ dst0_,
    void* __restrict__ dst1_, const float* __restrict__ filt)
{
    __shared__ float s_sh[SROWS][SCOLS];

    const int tid  = threadIdx.x;
    const int bid  = (int)blockIdx.x;
    const int tile = bid & 7;
    const int c    = (bid >> 3) & 63;
    const int b    = bid >> 9;
    const int h0   = tile * TH;
    const int wave = tid >> 6;
    const int lane = tid & 63;
    const int plane_idx = b * C_ + c;
    const __half* src = (const __half*)in_ + (size_t)plane_idx * PPLANE;

    // LDS halo cols [0,4) and [260,264): zero once; staging never touches them
    if (tid < 80) {
        const int r = tid >> 1;
        *(float4*)&s_sh[r][(tid & 1) ? 260 : 0] = make_float4(0.f, 0.f, 0.f, 0.f);
    }

    // ---- stage parity-0 (rows h0-4 .. h0+35): load + convert + LDS write ----
    #pragma unroll
    for (int u = 0; u < 10; ++u) {
        const int r  = wave + u * 4;
        const int hr = h0 + r - 4;
        float4 v = make_float4(0.f, 0.f, 0.f, 0.f);
        if ((unsigned)hr < 256u) {                       // wave-uniform
            const __half* rowh = src + (size_t)hr * PSTRIDE;
            const int d  = -128 + hr + 4 + lane * 4;     // p0: off=-128, sign=+1
            const int mc = min(max(d & ~1, 0), 258);
            const h8 raw = *(const h8*)(rowh + mc);      // 4B-aligned 16B
            v = shear_avg_h(raw, d);
        }
        *(float4*)&s_sh[r][4 + lane * 4] = v;            // 16B-aligned
    }

    // ---- issue parity-1 loads (SAME rows, other col window) into regs ----
    h8 R[10] = {};
    #pragma unroll
    for (int u = 0; u < 10; ++u) {
        const int hr = h0 + wave + u * 4 - 4;
        if ((unsigned)hr < 256u) {                       // wave-uniform
            const __half* rowh = src + (size_t)hr * PSTRIDE;
            const int d  = 127 - hr + 4 + lane * 4;      // p1: off=127, sign=-1
            const int mc = min(max(d & ~1, 0), 258);
            R[u] = *(const h8*)(rowh + mc);
        }
    }
    __builtin_amdgcn_sched_barrier(0);   // pin: p1 loads issued before compute0

    const Factors F = mk_factors(filt);

    __syncthreads();
    compute_store<DST_H>(s_sh, dst0_, F, plane_idx, c, h0, bid == 0);
    __syncthreads();                     // p0's s_sh reads done

    // ---- write parity-1 (loads completed under compute0) ----
    #pragma unroll
    for (int u = 0; u < 10; ++u) {
        const int r  = wave + u * 4;
        const int hr = h0 + r - 4;
        float4 v = make_float4(0.f, 0.f, 0.f, 0.f);
        if ((unsigned)hr < 256u) {
            const int d = 127 - hr + 4 + lane * 4;
            v = shear_avg_h(R[u], d);
        }
        *(float4*)&s_sh[r][4 + lane * 4] = v;
    }
    __syncthreads();
    compute_store<DST_H>(s_sh, dst1_, F, plane_idx, c, h0, bid == 0);
}

// ---------- x-source kernel (fp32 unpadded input), R9/R10 path unchanged ----------
__global__ __launch_bounds__(256) void shear_x_kernel(
    const float* __restrict__ in, void* __restrict__ dst_,
    const float* __restrict__ filt, int parity)
{
    __shared__ float s_sh[SROWS][SCOLS];

    const int tid  = threadIdx.x;
    const int bid  = (int)blockIdx.x;
    const int tile = bid & 7;
    const int c    = (bid >> 3) & 63;
    const int b    = bid >> 9;
    const int h0   = tile * TH;
    const int sign = parity ? -1 : 1;
    const int off  = parity ? 127 : -128;
    const int plane_idx = b * C_ + c;

    {
        const int wave = tid >> 6;
        const int lane = tid & 63;

        if (tid < 80) {
            const int r = tid >> 1;
            *(float4*)&s_sh[r][(tid & 1) ? 260 : 0] = make_float4(0.f, 0.f, 0.f, 0.f);
        }

        #pragma unroll
        for (int u = 0; u < 10; ++u) {
            const int r  = wave + u * 4;
            const int hr = h0 + r - 4;
            float4 v = make_float4(0.f, 0.f, 0.f, 0.f);
            if ((unsigned)hr < 256u) {
                const float* row = in + (size_t)plane_idx * (H_ * W_)
                                      + (size_t)hr * W_;
                const int c0 = off + sign * hr + lane * 4;
                float t0 = row[min(max(c0,     0), 255)];
                float t1 = row[min(max(c0 + 1, 0), 255)];
                float t2 = row[min(max(c0 + 2, 0), 255)];
                float t3 = row[min(max(c0 + 3, 0), 255)];
                float t4 = row[min(max(c0 + 4, 0), 255)];
                t0 = ((unsigned)c0       < 256u) ? t0 : 0.f;
                t1 = ((unsigned)(c0 + 1) < 256u) ? t1 : 0.f;
                t2 = ((unsigned)(c0 + 2) < 256u) ? t2 : 0.f;
                t3 = ((unsigned)(c0 + 3) < 256u) ? t3 : 0.f;
                t4 = ((unsigned)(c0 + 4) < 256u) ? t4 : 0.f;
                v.x = 0.5f * (t0 + t1);
                v.y = 0.5f * (t1 + t2);
                v.z = 0.5f * (t2 + t3);
                v.w = 0.5f * (t3 + t4);
            }
            *(float4*)&s_sh[r][4 + lane * 4] = v;
        }
    }

    const Factors F = mk_factors(filt);
    __syncthreads();
    compute_store<true>(s_sh, dst_, F, plane_idx, c, h0, bid == 0);
}

extern "C" void kernel_launch(void* const* d_in, const int* in_sizes, int n_in,
                              void* d_out, int out_size, void* d_ws, size_t ws_size,
                              hipStream_t stream) {
    const float* x    = (const float*)d_in[0];
    const float* filt = (const float*)d_in[1];
    float* out = (float*)d_out;
    void*  wsb = d_ws;                  // 64 MiB spare: ABh lives here
    const size_t N = (size_t)B_ * C_ * H_ * W_;   // floats per 64MiB slot

    float* S[8];
    for (int k = 0; k < 8; ++k) S[k] = out + (size_t)k * N;

    // fp16 padded intermediates inside final slots (33.3 MiB per 64 MiB slot)
    void* Bh  = (void*)S[0];
    void* BAh = (void*)S[2];
    void* BBh = (void*)S[3];
    void* Ah  = (void*)S[1];
    void* AAh = (void*)S[2];            // reused after BAh dead
    void* ABh = wsb;

    const dim3 block(256);
    const dim3 grid(NPB);

    #define LX(src, dst, par) \
        shear_x_kernel<<<grid, block, 0, stream>>>(src, dst, filt, par)
    #define P(DH, src, d0, d1) \
        shear_pair_kernel<DH><<<grid, block, 0, stream>>>(src, d0, d1, filt)

    // B-subtree
    LX(x, Bh, 1);                        // 1: B
    P(true , Bh,  BAh,  BBh );           // 2: BA (p0), BB (p1)
    P(false, BAh, S[4], S[5]);           // 3: out4, out5
    P(false, BBh, S[6], S[7]);           // 4: out6, out7
    // A-subtree
    LX(x, Ah, 0);                        // 5: A
    P(true , Ah,  AAh,  ABh );           // 6: AA (S2: BAh dead), AB -> ws
    P(false, AAh, S[0], S[1]);           // 7: out0 (Bh dead), out1 (Ah dead)
    P(false, ABh, S[2], S[3]);           // 8: out2 (AAh dead), out3 (BBh dead)
    #undef LX
    #undef P
}

// Round 12
// 361.920 us; speedup vs baseline: 2.3192x; 1.0161x over previous
//
#include <hip/hip_runtime.h>
#include <hip/hip_fp16.h>

// DirectionalFilterBank: 3-level binary tree of (shear ±1 -> depthwise 9x9 conv).
// shear(x,s)[h,w] = 0.5*(x[h,c0]+x[h,c0+1]), c0 = w + s*h + (s>0 ? -128 : 127).
// Filter rank-2 separable: filt_c = -(A (x) A) + (B (x) B) [+ center delta, c==0].
//
// Cost model (R6-R11): time ~ traffic/6.3TB/s + ~200us instr component; traffic
// is the lever that moves (R9 -94us, R11 -18us). R11 = 368us @ 1048MB, 8 launches.
// THIS ROUND: (1) pair the two x-sourced convs in one block (x read once: -64MB;
// p1's 50 fp32 staging regs held across compute0 -- no launch_bounds cap, ~150
// VGPR total, 3 blk/CU kept; R8's spill was the (256,3) cap + 2 staged tiles).
// (2) merge the two independent final launches BAh->o45 / BBh->o67 into one
// 4096-block launch (kills one full drain boundary). AAh/ABh finals can't merge
// (AAh lives in S2 which that launch writes). Traffic 984MB, 6 launches.
//
// Schedule + liveness (fp16 padded intermediates, 32.5MiB, inside 64MiB slots):
//  L1 xpair: x -> Ah(S3), Bh(S0)
//  L2 pair : Bh(S0) -> BAh(S1), BBh(S2)
//  L3 pair4: BAh(S1)->out4(S4),out5(S5); BBh(S2)->out6(S6),out7(S7)
//  L4 pair : Ah(S3) -> AAh(S2: BBh dead), ABh(ws)
//  L5 pair : AAh(S2) -> out0(S0: Bh dead), out1(S1: BAh dead)
//  L6 pair : ABh(ws) -> out2(S2: AAh dead), out3(S3: Ah dead)
// Each launch: reads disjoint from writes; finals written once, never after.

#define B_ 4
#define C_ 64
#define H_ 256
#define W_ 256
#define TH 32                 // output rows per tile
#define SROWS (TH + 8)        // 40 staged sheared rows
#define SCOLS (W_ + 8)        // 264 staged cols; LDS = 41.25 KiB (fp32)
#define NPB 2048              // blocks per conv-pair
#define PSTRIDE 260           // padded row stride in HALVES
#define PPLANE (H_ * PSTRIDE) // 66560 halves = 133120 B per plane

struct alignas(4) h8 { unsigned int u[4]; };   // 8 halves, 4B-aligned 16B load

struct Factors { float A0, A2, A4, A6, A8, B1, B3, B5, B7, vc[9]; };

static __device__ __forceinline__ Factors mk_factors(const float* __restrict__ filt)
{
    const float* f1 = filt + 81;           // channel 1: uniform for all c
    Factors F;
    F.A4 = sqrtf(fmaxf(-f1[4 * 9 + 4], 0.f));
    const float rA4 = 1.f / F.A4;
    F.A0 = -f1[0 * 9 + 4] * rA4;  F.A2 = -f1[2 * 9 + 4] * rA4;
    F.A6 = -f1[6 * 9 + 4] * rA4;  F.A8 = -f1[8 * 9 + 4] * rA4;
    F.B5 = sqrtf(fmaxf(f1[5 * 9 + 5], 0.f));
    const float rB5 = 1.f / F.B5;
    F.B1 = f1[1 * 9 + 5] * rB5;  F.B3 = f1[3 * 9 + 5] * rB5;
    F.B7 = f1[7 * 9 + 5] * rB5;
    F.vc[0] = -F.A0; F.vc[1] = F.B1; F.vc[2] = -F.A2; F.vc[3] = F.B3;
    F.vc[4] = -F.A4; F.vc[5] = F.B5; F.vc[6] = -F.A6; F.vc[7] = F.B7;
    F.vc[8] = -F.A8;
    return F;
}

// 16B fp16 window (8 halves from even index mc=clamp(d&~1,0,258)) -> sheared
// float4 for cols 4L..4L+3. d = first half index; stored pads guarantee zeros.
static __device__ __forceinline__ float4 shear_avg_h(const h8 raw, int d)
{
    union { h8 r; __half2 h2[4]; } U; U.r = raw;
    const bool qhi   = (d & 1) != 0;
    const bool valid = (unsigned)d < 260u;          // c0 in [-4,255]
    const float2 g01 = __half22float2(U.h2[0]);
    const float2 g23 = __half22float2(U.h2[1]);
    const float2 g45 = __half22float2(U.h2[2]);
    const float t0 = qhi ? g01.y : g01.x;
    const float t1 = qhi ? g23.x : g01.y;
    const float t2 = qhi ? g23.y : g23.x;
    const float t3 = qhi ? g45.x : g23.y;
    const float t4 = qhi ? g45.y : g45.x;
    float4 v;
    v.x = valid ? 0.5f * (t0 + t1) : 0.f;
    v.y = valid ? 0.5f * (t1 + t2) : 0.f;
    v.z = valid ? 0.5f * (t2 + t3) : 0.f;
    v.w = valid ? 0.5f * (t3 + t4) : 0.f;
    return v;
}

template<bool DST_H>
static __device__ __forceinline__ void compute_store(
    float (&s_sh)[SROWS][SCOLS], void* __restrict__ dst_, const Factors& F,
    int plane_idx, int c, int h0t, bool first_pad)
{
    const int tid  = threadIdx.x;
    const int rg   = tid >> 6;           // 0..3 -> out rows rg*8 .. rg*8+7
    const int lane = tid & 63;
    const int w0   = lane * 4;

    float acc[8][4];
    #pragma unroll
    for (int i = 0; i < 8; ++i)
        #pragma unroll
        for (int j = 0; j < 4; ++j) acc[i][j] = 0.f;

    __builtin_amdgcn_s_setprio(1);
    #pragma unroll
    for (int t = 0; t < 16; ++t) {       // staged rows rg*8 + t
        const int rr = rg * 8 + t;
        const float4 sa  = *(const float4*)&s_sh[rr][w0];
        const float4 sb  = *(const float4*)&s_sh[rr][w0 + 4];
        const float4 sc4 = *(const float4*)&s_sh[rr][w0 + 8];
        const float s[12] = {sa.x, sa.y, sa.z, sa.w,
                             sb.x, sb.y, sb.z, sb.w,
                             sc4.x, sc4.y, sc4.z, sc4.w};
        float ha[4], hb[4];
        #pragma unroll
        for (int j = 0; j < 4; ++j) {
            ha[j] = fmaf(F.A8, s[j + 8],
                    fmaf(F.A6, s[j + 6],
                    fmaf(F.A4, s[j + 4],
                    fmaf(F.A2, s[j + 2], F.A0 * s[j]))));
            hb[j] = fmaf(F.B7, s[j + 7],
                    fmaf(F.B5, s[j + 5],
                    fmaf(F.B3, s[j + 3], F.B1 * s[j + 1])));
        }
        #pragma unroll
        for (int i = 0; i < 8; ++i) {
            const int ky = t - i;        // compile-time after unroll
            if (ky >= 0 && ky < 9) {
                #pragma unroll
                for (int j = 0; j < 4; ++j) {
                    const float hv = (ky & 1) ? hb[j] : ha[j];
                    acc[i][j] = fmaf(F.vc[ky], hv, acc[i][j]);
                }
            }
        }
    }
    __builtin_amdgcn_s_setprio(0);

    // channel-0 delta: += sheared image value at the output location
    if (c == 0) {
        #pragma unroll
        for (int i = 0; i < 8; ++i) {
            const float4 sv = *(const float4*)&s_sh[rg * 8 + i + 4][w0 + 4];
            acc[i][0] += sv.x; acc[i][1] += sv.y; acc[i][2] += sv.z; acc[i][3] += sv.w;
        }
    }

    if (DST_H) {
        __half* plane = (__half*)dst_ + (size_t)plane_idx * PPLANE;
        // zero next-row left-pad (4 halves = 8B); chains across rows/planes
        if (lane < 8) {
            uint2 z; z.x = 0u; z.y = 0u;
            *(uint2*)(plane + (size_t)(h0t + rg * 8 + lane + 1) * PSTRIDE) = z;
        }
        if (first_pad && tid == 8) {     // very first plane's row-0 left pad
            uint2 z; z.x = 0u; z.y = 0u;
            *(uint2*)dst_ = z;
        }
        __half* optr = plane + (size_t)(h0t + rg * 8) * PSTRIDE + 4 + (lane * 4);
        #pragma unroll
        for (int i = 0; i < 8; ++i) {
            union { __half2 h2; unsigned int u; } p0, p1;
            p0.h2 = __floats2half2_rn(acc[i][0], acc[i][1]);
            p1.h2 = __floats2half2_rn(acc[i][2], acc[i][3]);
            uint2 pk; pk.x = p0.u; pk.y = p1.u;
            *(uint2*)(optr + (size_t)i * PSTRIDE) = pk;   // 8B-aligned
        }
    } else {
        float* optr = (float*)dst_
            + (((size_t)plane_idx) * H_ + h0t + rg * 8) * (size_t)W_ + (lane * 4);
        #pragma unroll
        for (int i = 0; i < 8; ++i) {
            const float4 v = {acc[i][0], acc[i][1], acc[i][2], acc[i][3]};
            *(float4*)(optr + (size_t)i * W_) = v;
        }
    }
}

// ---- shared body: fp16 padded source; one tile, BOTH parities ----
// p0: sign=+1 off=-128 -> dst0;  p1: sign=-1 off=127 -> dst1.  p1's loads
// re-read p0's rows (L2-hot) and fly under compute0.
template<bool DST_H>
static __device__ __forceinline__ void pair_body(
    const void* __restrict__ in_, void* __restrict__ dst0_,
    void* __restrict__ dst1_, const float* __restrict__ filt, int inner)
{
    __shared__ float s_sh[SROWS][SCOLS];

    const int tid  = threadIdx.x;
    const int tile = inner & 7;
    const int c    = (inner >> 3) & 63;
    const int b    = inner >> 9;
    const int h0   = tile * TH;
    const int wave = tid >> 6;
    const int lane = tid & 63;
    const int plane_idx = b * C_ + c;
    const __half* src = (const __half*)in_ + (size_t)plane_idx * PPLANE;

    // LDS halo cols [0,4) and [260,264): zero once; staging never touches them
    if (tid < 80) {
        const int r = tid >> 1;
        *(float4*)&s_sh[r][(tid & 1) ? 260 : 0] = make_float4(0.f, 0.f, 0.f, 0.f);
    }

    // ---- stage parity-0 (rows h0-4 .. h0+35): load + convert + LDS write ----
    #pragma unroll
    for (int u = 0; u < 10; ++u) {
        const int r  = wave + u * 4;
        const int hr = h0 + r - 4;
        float4 v = make_float4(0.f, 0.f, 0.f, 0.f);
        if ((unsigned)hr < 256u) {                       // wave-uniform
            const __half* rowh = src + (size_t)hr * PSTRIDE;
            const int d  = -128 + hr + 4 + lane * 4;     // p0: off=-128, sign=+1
            const int mc = min(max(d & ~1, 0), 258);
            const h8 raw = *(const h8*)(rowh + mc);      // 4B-aligned 16B
            v = shear_avg_h(raw, d);
        }
        *(float4*)&s_sh[r][4 + lane * 4] = v;            // 16B-aligned
    }

    // ---- issue parity-1 loads (SAME rows, other col window) into regs ----
    h8 R[10] = {};
    #pragma unroll
    for (int u = 0; u < 10; ++u) {
        const int hr = h0 + wave + u * 4 - 4;
        if ((unsigned)hr < 256u) {                       // wave-uniform
            const __half* rowh = src + (size_t)hr * PSTRIDE;
            const int d  = 127 - hr + 4 + lane * 4;      // p1: off=127, sign=-1
            const int mc = min(max(d & ~1, 0), 258);
            R[u] = *(const h8*)(rowh + mc);
        }
    }
    __builtin_amdgcn_sched_barrier(0);   // pin: p1 loads issued before compute0

    const Factors F = mk_factors(filt);

    __syncthreads();
    compute_store<DST_H>(s_sh, dst0_, F, plane_idx, c, h0, inner == 0);
    __syncthreads();                     // p0's s_sh reads done

    // ---- write parity-1 (loads completed under compute0) ----
    #pragma unroll
    for (int u = 0; u < 10; ++u) {
        const int r  = wave + u * 4;
        const int hr = h0 + r - 4;
        float4 v = make_float4(0.f, 0.f, 0.f, 0.f);
        if ((unsigned)hr < 256u) {
            const int d = 127 - hr + 4 + lane * 4;
            v = shear_avg_h(R[u], d);
        }
        *(float4*)&s_sh[r][4 + lane * 4] = v;
    }
    __syncthreads();
    compute_store<DST_H>(s_sh, dst1_, F, plane_idx, c, h0, inner == 0);
}

template<bool DST_H>
__global__ __launch_bounds__(256) void shear_pair_kernel(
    const void* __restrict__ in_, void* __restrict__ dst0_,
    void* __restrict__ dst1_, const float* __restrict__ filt)
{
    pair_body<DST_H>(in_, dst0_, dst1_, filt, (int)blockIdx.x);
}

// merged independent pair: blocks [0,2048) do s0->(d00,d01); [2048,4096) s1->(d10,d11)
__global__ __launch_bounds__(256) void shear_pair4_kernel(
    const void* __restrict__ s0, const void* __restrict__ s1,
    void* __restrict__ d00, void* __restrict__ d01,
    void* __restrict__ d10, void* __restrict__ d11,
    const float* __restrict__ filt)
{
    const int bid   = (int)blockIdx.x;
    const int k     = bid >> 11;
    const int inner = bid & 2047;
    pair_body<false>(k ? s1 : s0, k ? d10 : d00, k ? d11 : d01, filt, inner);
}

// ---- x-source pair: fp32 unpadded x; one tile, BOTH parities -> two fp16 dsts ----
// p1's 10x5 fp32 staging values held in regs (50 VGPR) across compute0.
__global__ __launch_bounds__(256) void shear_xpair_kernel(
    const float* __restrict__ in, void* __restrict__ dst0_,
    void* __restrict__ dst1_, const float* __restrict__ filt)
{
    __shared__ float s_sh[SROWS][SCOLS];

    const int tid  = threadIdx.x;
    const int bid  = (int)blockIdx.x;
    const int tile = bid & 7;
    const int c    = (bid >> 3) & 63;
    const int b    = bid >> 9;
    const int h0   = tile * TH;
    const int wave = tid >> 6;
    const int lane = tid & 63;
    const int plane_idx = b * C_ + c;
    const float* plane = in + (size_t)plane_idx * (H_ * W_);

    if (tid < 80) {
        const int r = tid >> 1;
        *(float4*)&s_sh[r][(tid & 1) ? 260 : 0] = make_float4(0.f, 0.f, 0.f, 0.f);
    }

    // ---- stage parity-0 (off=-128, sign=+1): branchless clamp + masks ----
    #pragma unroll
    for (int u = 0; u < 10; ++u) {
        const int r  = wave + u * 4;
        const int hr = h0 + r - 4;
        float4 v = make_float4(0.f, 0.f, 0.f, 0.f);
        if ((unsigned)hr < 256u) {
            const float* row = plane + (size_t)hr * W_;
            const int c0 = -128 + hr + lane * 4;
            float t0 = row[min(max(c0,     0), 255)];
            float t1 = row[min(max(c0 + 1, 0), 255)];
            float t2 = row[min(max(c0 + 2, 0), 255)];
            float t3 = row[min(max(c0 + 3, 0), 255)];
            float t4 = row[min(max(c0 + 4, 0), 255)];
            t0 = ((unsigned)c0       < 256u) ? t0 : 0.f;
            t1 = ((unsigned)(c0 + 1) < 256u) ? t1 : 0.f;
            t2 = ((unsigned)(c0 + 2) < 256u) ? t2 : 0.f;
            t3 = ((unsigned)(c0 + 3) < 256u) ? t3 : 0.f;
            t4 = ((unsigned)(c0 + 4) < 256u) ? t4 : 0.f;
            v.x = 0.5f * (t0 + t1);
            v.y = 0.5f * (t1 + t2);
            v.z = 0.5f * (t2 + t3);
            v.w = 0.5f * (t3 + t4);
        }
        *(float4*)&s_sh[r][4 + lane * 4] = v;
    }

    // ---- issue parity-1 loads (off=127, sign=-1) into regs: 50 VGPR held ----
    float Ra[10][5];
    #pragma unroll
    for (int u = 0; u < 10; ++u) {
        #pragma unroll
        for (int q = 0; q < 5; ++q) Ra[u][q] = 0.f;
        const int hr = h0 + wave + u * 4 - 4;
        if ((unsigned)hr < 256u) {
            const float* row = plane + (size_t)hr * W_;
            const int c0 = 127 - hr + lane * 4;
            Ra[u][0] = row[min(max(c0,     0), 255)];
            Ra[u][1] = row[min(max(c0 + 1, 0), 255)];
            Ra[u][2] = row[min(max(c0 + 2, 0), 255)];
            Ra[u][3] = row[min(max(c0 + 3, 0), 255)];
            Ra[u][4] = row[min(max(c0 + 4, 0), 255)];
        }
    }
    __builtin_amdgcn_sched_barrier(0);   // pin: p1 loads issued before compute0

    const Factors F = mk_factors(filt);

    __syncthreads();
    compute_store<true>(s_sh, dst0_, F, plane_idx, c, h0, bid == 0);
    __syncthreads();

    // ---- write parity-1 (masks applied now; loads drained under compute0) ----
    #pragma unroll
    for (int u = 0; u < 10; ++u) {
        const int r  = wave + u * 4;
        const int hr = h0 + r - 4;
        float4 v = make_float4(0.f, 0.f, 0.f, 0.f);
        if ((unsigned)hr < 256u) {
            const int c0 = 127 - hr + lane * 4;
            const float t0 = ((unsigned)c0       < 256u) ? Ra[u][0] : 0.f;
            const float t1 = ((unsigned)(c0 + 1) < 256u) ? Ra[u][1] : 0.f;
            const float t2 = ((unsigned)(c0 + 2) < 256u) ? Ra[u][2] : 0.f;
            const float t3 = ((unsigned)(c0 + 3) < 256u) ? Ra[u][3] : 0.f;
            const float t4 = ((unsigned)(c0 + 4) < 256u) ? Ra[u][4] : 0.f;
            v.x = 0.5f * (t0 + t1);
            v.y = 0.5f * (t1 + t2);
            v.z = 0.5f * (t2 + t3);
            v.w = 0.5f * (t3 + t4);
        }
        *(float4*)&s_sh[r][4 + lane * 4] = v;
    }
    __syncthreads();
    compute_store<true>(s_sh, dst1_, F, plane_idx, c, h0, bid == 0);
}

extern "C" void kernel_launch(void* const* d_in, const int* in_sizes, int n_in,
                              void* d_out, int out_size, void* d_ws, size_t ws_size,
                              hipStream_t stream) {
    const float* x    = (const float*)d_in[0];
    const float* filt = (const float*)d_in[1];
    float* out = (float*)d_out;
    void*  wsb = d_ws;                  // 64 MiB spare: ABh lives here
    const size_t N = (size_t)B_ * C_ * H_ * W_;   // floats per 64MiB slot

    float* S[8];
    for (int k = 0; k < 8; ++k) S[k] = out + (size_t)k * N;

    // fp16 padded intermediates (32.5 MiB) inside 64 MiB final slots
    void* Ah  = (void*)S[3];
    void* Bh  = (void*)S[0];
    void* BAh = (void*)S[1];
    void* BBh = (void*)S[2];
    void* AAh = (void*)S[2];            // reused after BBh dead (L3)
    void* ABh = wsb;

    const dim3 block(256);
    const dim3 grid(NPB);
    const dim3 grid4(2 * NPB);

    // L1: x -> Ah (p0), Bh (p1); x read ONCE
    shear_xpair_kernel<<<grid, block, 0, stream>>>(x, Ah, Bh, filt);
    // L2: Bh -> BAh (p0), BBh (p1)
    shear_pair_kernel<true><<<grid, block, 0, stream>>>(Bh, BAh, BBh, filt);
    // L3: merged finals: BAh -> out4,out5 ; BBh -> out6,out7
    shear_pair4_kernel<<<grid4, block, 0, stream>>>(
        BAh, BBh, (void*)S[4], (void*)S[5], (void*)S[6], (void*)S[7], filt);
    // L4: Ah -> AAh (S2: BBh dead), ABh (ws)
    shear_pair_kernel<true><<<grid, block, 0, stream>>>(Ah, AAh, ABh, filt);
    // L5: AAh -> out0 (S0: Bh dead), out1 (S1: BAh dead)
    shear_pair_kernel<false><<<grid, block, 0, stream>>>(AAh, (void*)S[0],
                                                         (void*)S[1], filt);
    // L6: ABh -> out2 (S2: AAh dead), out3 (S3: Ah dead)
    shear_pair_kernel<false><<<grid, block, 0, stream>>>(ABh, (void*)S[2],
                                                         (void*)S[3], filt);
}